// Round 1
// baseline (4538.840 us; speedup 1.0000x reference)
//
#include <hip/hip_runtime.h>
#include <hip/hip_fp16.h>

// GRU (Keras reset_after=True), B=64 T=512 D=256 H=1024.
// Persistent cooperative kernel: 256 WGs (1/CU), weights register-resident,
// per-step group barrier via LLC flags, h double-buffered in f16.

#define NB 64
#define NT 512
#define ND 256
#define NH 1024
#define NG 3072  // 3H

typedef _Float16 f16;
typedef __attribute__((ext_vector_type(8))) _Float16 f16x8;
typedef __attribute__((ext_vector_type(4))) float f32x4;

// ---- prep: pack U [H,3H] f32 -> fragment-layout f16 ----
// Up index: (((jb*3 + g)*32 + kt)*64 + l)*8 + e
// value  : U[k][col], k = kt*32 + (l>>4)*8 + e, col = g*NH + jb*16 + (l&15)
__global__ void pack_u_kernel(const float* __restrict__ U, f16* __restrict__ Up) {
    int idx = blockIdx.x * 256 + threadIdx.x;      // 64*3*32*64 = 393216
    int l  = idx & 63;
    int kt = (idx >> 6) & 31;
    int r  = idx >> 11;                            // jb*3 + g
    int g  = r % 3, jb = r / 3;
    int col = g * NH + jb * 16 + (l & 15);
    int k0  = kt * 32 + (l >> 4) * 8;
    f16x8 v;
#pragma unroll
    for (int e = 0; e < 8; ++e) v[e] = (f16)U[(size_t)(k0 + e) * NG + col];
    *(f16x8*)(Up + (size_t)idx * 8) = v;
}

// Wp index: (((jb*3 + g)*8 + kt)*64 + l)*8 + e  (K=256 -> 8 ktiles)
__global__ void pack_w_kernel(const float* __restrict__ W, f16* __restrict__ Wp) {
    int idx = blockIdx.x * 256 + threadIdx.x;      // 64*3*8*64 = 98304
    int l  = idx & 63;
    int kt = (idx >> 6) & 7;
    int r  = idx >> 9;
    int g  = r % 3, jb = r / 3;
    int col = g * NH + jb * 16 + (l & 15);
    int k0  = kt * 32 + (l >> 4) * 8;
    f16x8 v;
#pragma unroll
    for (int e = 0; e < 8; ++e) v[e] = (f16)W[(size_t)(k0 + e) * NG + col];
    *(f16x8*)(Wp + (size_t)idx * 8) = v;
}

// bs[0..H): bi_z+br_z ; bs[H..2H): bi_r+br_r ; bs[2H..3H): bi_h ; bs[3H..4H): br_h
__global__ void bias_kernel(const float* __restrict__ bi, const float* __restrict__ br,
                            float* __restrict__ bs) {
    int j = threadIdx.x;  // 1024
    bs[j]          = bi[j] + br[j];
    bs[NH + j]     = bi[NH + j] + br[NH + j];
    bs[2 * NH + j] = bi[2 * NH + j];
    bs[3 * NH + j] = br[2 * NH + j];
}

__global__ __launch_bounds__(256, 1) void gru_kernel(
    const float* __restrict__ x,        // [B,T,D] f32
    const float* __restrict__ h0,       // [B,H]   f32
    const f16*   __restrict__ Up,
    const f16*   __restrict__ Wp,
    const float* __restrict__ bs,       // [4][H]
    unsigned short* __restrict__ h16,   // [2][64][1024] f16 bits (double buffer)
    unsigned int*  __restrict__ flags,  // [4][64]
    float* __restrict__ out)            // y [B,T,H] then state [B,H]
{
    const int tid = threadIdx.x;
    const int wg  = blockIdx.x;
    const int jb  = wg & 63;     // column-slice 16 j's
    const int bb  = wg >> 6;     // batch-group (16 batches)
    const int w   = tid >> 6;    // wave 0..3 (K-split)
    const int l   = tid & 63;
    const int lrow   = l & 15;   // A row / B col within tile
    const int lchunk = l >> 4;   // k-chunk

    __shared__ float red[4][4][256];   // [wave][tile: z,r,xh,rh][lane*4+i]

    // ---- persistent B fragments in registers (30 frags = 120 VGPR of f16) ----
    f16x8 uz[8], ur[8], uh[8], wz[2], wr[2], wh[2];
    {
        const f16* ub = Up + (size_t)jb * 3 * 32 * 512;
#pragma unroll
        for (int q = 0; q < 8; ++q) {
            int kt = w * 8 + q;
            uz[q] = *(const f16x8*)(ub + ((size_t)(0 * 32 + kt) * 64 + l) * 8);
            ur[q] = *(const f16x8*)(ub + ((size_t)(1 * 32 + kt) * 64 + l) * 8);
            uh[q] = *(const f16x8*)(ub + ((size_t)(2 * 32 + kt) * 64 + l) * 8);
        }
        const f16* wb = Wp + (size_t)jb * 3 * 8 * 512;
#pragma unroll
        for (int m = 0; m < 2; ++m) {
            int kt = w * 2 + m;
            wz[m] = *(const f16x8*)(wb + ((size_t)(0 * 8 + kt) * 64 + l) * 8);
            wr[m] = *(const f16x8*)(wb + ((size_t)(1 * 8 + kt) * 64 + l) * 8);
            wh[m] = *(const f16x8*)(wb + ((size_t)(2 * 8 + kt) * 64 + l) * 8);
        }
    }

    // ---- gates-phase thread mapping: tid = gb*16 + gj  <->  (batch, j) ----
    const int gb = tid >> 4, gj = tid & 15;
    const int bglob = bb * 16 + gb;
    const int jglob = jb * 16 + gj;
    const float bz  = bs[jglob];
    const float brg = bs[NH + jglob];
    const float bih = bs[2 * NH + jglob];
    const float brh = bs[3 * NH + jglob];
    float hown = h0[(size_t)bglob * NH + jglob];   // f32 master state

    unsigned int* h32 = (unsigned int*)h16;

    // publish h^0 into buffer 0 (write-through agent stores)
    {
        union { f16 h; unsigned short u; } cv; cv.h = (f16)hown;
        unsigned int hi = (unsigned int)__shfl_down((int)cv.u, 1);
        if ((gj & 1) == 0) {
            unsigned int v = (unsigned int)cv.u | (hi << 16);
            __hip_atomic_store(&h32[(size_t)bglob * 512 + (jglob >> 1)], v,
                               __ATOMIC_RELAXED, __HIP_MEMORY_SCOPE_AGENT);
        }
    }
    __syncthreads();   // drains vmcnt -> stores are at LLC
    if (tid == 0)
        __hip_atomic_store(&flags[wg], 1u, __ATOMIC_RELEASE, __HIP_MEMORY_SCOPE_AGENT);

    unsigned int* myf = flags + bb * 64;
    const int arow = bb * 16 + lrow;

    for (int t = 0; t < NT; ++t) {
        // ---- wait: all 64 WGs of this batch-group published h^t ----
        if (tid < 64) {
            while (__hip_atomic_load(&myf[tid], __ATOMIC_RELAXED,
                                     __HIP_MEMORY_SCOPE_AGENT) < (unsigned int)(t + 1)) {
                __builtin_amdgcn_s_sleep(1);
            }
            __builtin_amdgcn_fence(__ATOMIC_ACQUIRE, "agent");
        }
        __syncthreads();

        // ---- A fragments: h^t (f16, LLC) and x_t (f32 -> f16) ----
        const unsigned short* hb =
            h16 + (size_t)(t & 1) * 65536 + (size_t)arow * NH + lchunk * 8;
        f16x8 au[8];
#pragma unroll
        for (int q = 0; q < 8; ++q)
            au[q] = *(const f16x8*)(hb + (w * 8 + q) * 32);

        f16x8 axm[2];
        const float* xb = x + ((size_t)arow * NT + t) * ND + lchunk * 8;
#pragma unroll
        for (int m = 0; m < 2; ++m) {
            const float* p = xb + (w * 2 + m) * 32;
            f32x4 a0 = *(const f32x4*)p;
            f32x4 a1 = *(const f32x4*)(p + 4);
            f16x8 v;
#pragma unroll
            for (int e = 0; e < 4; ++e) { v[e] = (f16)a0[e]; v[4 + e] = (f16)a1[e]; }
            axm[m] = v;
        }

        // ---- MFMA: K-split partials (z, r, xh, rh) ----
        f32x4 acc_z = {0,0,0,0}, acc_r = {0,0,0,0}, acc_xh = {0,0,0,0}, acc_rh = {0,0,0,0};
#pragma unroll
        for (int q = 0; q < 8; ++q) {
            acc_z  = __builtin_amdgcn_mfma_f32_16x16x32_f16(au[q], uz[q], acc_z, 0, 0, 0);
            acc_r  = __builtin_amdgcn_mfma_f32_16x16x32_f16(au[q], ur[q], acc_r, 0, 0, 0);
            acc_rh = __builtin_amdgcn_mfma_f32_16x16x32_f16(au[q], uh[q], acc_rh, 0, 0, 0);
        }
#pragma unroll
        for (int m = 0; m < 2; ++m) {
            acc_z  = __builtin_amdgcn_mfma_f32_16x16x32_f16(axm[m], wz[m], acc_z, 0, 0, 0);
            acc_r  = __builtin_amdgcn_mfma_f32_16x16x32_f16(axm[m], wr[m], acc_r, 0, 0, 0);
            acc_xh = __builtin_amdgcn_mfma_f32_16x16x32_f16(axm[m], wh[m], acc_xh, 0, 0, 0);
        }

        // ---- deterministic cross-wave reduction via LDS ----
        *(f32x4*)&red[w][0][l * 4] = acc_z;
        *(f32x4*)&red[w][1][l * 4] = acc_r;
        *(f32x4*)&red[w][2][l * 4] = acc_xh;
        *(f32x4*)&red[w][3][l * 4] = acc_rh;
        __syncthreads();

        const int li = ((((gb >> 2) << 4) | gj) << 2) + (gb & 3);
        float sz = 0.f, sr = 0.f, sxh = 0.f, srh = 0.f;
#pragma unroll
        for (int ww = 0; ww < 4; ++ww) {
            sz  += red[ww][0][li];
            sr  += red[ww][1][li];
            sxh += red[ww][2][li];
            srh += red[ww][3][li];
        }

        // ---- gates ----
        float zg = 1.f / (1.f + __expf(-(sz + bz)));
        float rg = 1.f / (1.f + __expf(-(sr + brg)));
        float ta = sxh + bih + rg * (srh + brh);
        float e2 = __expf(2.f * ta);
        float hh = (e2 - 1.f) / (e2 + 1.f);
        float hn = zg * hown + (1.f - zg) * hh;
        hown = hn;
        out[((size_t)bglob * NT + t) * NH + jglob] = hn;

        // ---- publish h^{t+1} into buffer (t+1)&1 ----
        union { f16 h; unsigned short u; } cv; cv.h = (f16)hn;
        unsigned int hi = (unsigned int)__shfl_down((int)cv.u, 1);
        if ((gj & 1) == 0) {
            unsigned int v = (unsigned int)cv.u | (hi << 16);
            __hip_atomic_store(&h32[(size_t)((t + 1) & 1) * 32768 +
                                    (size_t)bglob * 512 + (jglob >> 1)], v,
                               __ATOMIC_RELAXED, __HIP_MEMORY_SCOPE_AGENT);
        }
        __syncthreads();   // drain publish stores before flag
        if (tid == 0)
            __hip_atomic_store(&flags[wg], (unsigned int)(t + 2),
                               __ATOMIC_RELEASE, __HIP_MEMORY_SCOPE_AGENT);
    }

    // final state
    out[(size_t)NB * NT * NH + (size_t)bglob * NH + jglob] = hown;
}

extern "C" void kernel_launch(void* const* d_in, const int* in_sizes, int n_in,
                              void* d_out, int out_size, void* d_ws, size_t ws_size,
                              hipStream_t stream) {
    const float* x  = (const float*)d_in[0];
    const float* h0 = (const float*)d_in[1];
    const float* W  = (const float*)d_in[2];
    const float* U  = (const float*)d_in[3];
    const float* bi = (const float*)d_in[4];
    const float* br = (const float*)d_in[5];
    float* out = (float*)d_out;

    char* ws = (char*)d_ws;
    f16* Up            = (f16*)ws;                                   // 6,291,456 B
    f16* Wp            = (f16*)(ws + 6291456);                       // 1,572,864 B
    float* bs          = (float*)(ws + 6291456 + 1572864);           // 16 KB
    unsigned short* h16= (unsigned short*)(ws + 6291456 + 1572864 + 16384);     // 256 KB
    unsigned int* flags= (unsigned int*)(ws + 6291456 + 1572864 + 16384 + 262144); // 1 KB

    hipMemsetAsync(flags, 0, 256 * sizeof(unsigned int), stream);
    pack_u_kernel<<<1536, 256, 0, stream>>>(U, Up);
    pack_w_kernel<<<384, 256, 0, stream>>>(W, Wp);
    bias_kernel<<<1, 1024, 0, stream>>>(bi, br, bs);

    void* args[] = { (void*)&x, (void*)&h0, (void*)&Up, (void*)&Wp, (void*)&bs,
                     (void*)&h16, (void*)&flags, (void*)&out };
    hipLaunchCooperativeKernel((const void*)gru_kernel, dim3(256), dim3(256),
                               args, 0, stream);
}

// Round 2
// 3749.310 us; speedup vs baseline: 1.2106x; 1.2106x over previous
//
#include <hip/hip_runtime.h>
#include <hip/hip_fp16.h>

// GRU (Keras reset_after=True), B=64 T=512 D=256 H=1024.
// Persistent cooperative kernel: 256 WGs (1/CU), weights register-resident.
// Fence-free cross-WG step protocol: h + flags via RELAXED agent atomics only
// (LLC-direct, no buffer_wbl2 / buffer_inv per step); ordering via explicit
// s_waitcnt vmcnt(0) before flag publish.

#define NB 64
#define NT 512
#define ND 256
#define NH 1024
#define NG 3072  // 3H

typedef _Float16 f16;
typedef __attribute__((ext_vector_type(8))) _Float16 f16x8;
typedef __attribute__((ext_vector_type(4))) float f32x4;

// ---- prep: pack U [H,3H] f32 -> fragment-layout f16 ----
// Up index: (((jb*3 + g)*32 + kt)*64 + l)*8 + e
// value  : U[k][col], k = kt*32 + (l>>4)*8 + e, col = g*NH + jb*16 + (l&15)
__global__ void pack_u_kernel(const float* __restrict__ U, f16* __restrict__ Up) {
    int idx = blockIdx.x * 256 + threadIdx.x;      // 64*3*32*64 = 393216
    int l  = idx & 63;
    int kt = (idx >> 6) & 31;
    int r  = idx >> 11;                            // jb*3 + g
    int g  = r % 3, jb = r / 3;
    int col = g * NH + jb * 16 + (l & 15);
    int k0  = kt * 32 + (l >> 4) * 8;
    f16x8 v;
#pragma unroll
    for (int e = 0; e < 8; ++e) v[e] = (f16)U[(size_t)(k0 + e) * NG + col];
    *(f16x8*)(Up + (size_t)idx * 8) = v;
}

// Wp index: (((jb*3 + g)*8 + kt)*64 + l)*8 + e  (K=256 -> 8 ktiles)
__global__ void pack_w_kernel(const float* __restrict__ W, f16* __restrict__ Wp) {
    int idx = blockIdx.x * 256 + threadIdx.x;      // 64*3*8*64 = 98304
    int l  = idx & 63;
    int kt = (idx >> 6) & 7;
    int r  = idx >> 9;
    int g  = r % 3, jb = r / 3;
    int col = g * NH + jb * 16 + (l & 15);
    int k0  = kt * 32 + (l >> 4) * 8;
    f16x8 v;
#pragma unroll
    for (int e = 0; e < 8; ++e) v[e] = (f16)W[(size_t)(k0 + e) * NG + col];
    *(f16x8*)(Wp + (size_t)idx * 8) = v;
}

// bs[0..H): bi_z+br_z ; bs[H..2H): bi_r+br_r ; bs[2H..3H): bi_h ; bs[3H..4H): br_h
__global__ void bias_kernel(const float* __restrict__ bi, const float* __restrict__ br,
                            float* __restrict__ bs) {
    int j = threadIdx.x;  // 1024
    bs[j]          = bi[j] + br[j];
    bs[NH + j]     = bi[NH + j] + br[NH + j];
    bs[2 * NH + j] = bi[2 * NH + j];
    bs[3 * NH + j] = br[2 * NH + j];
}

__global__ __launch_bounds__(256, 1) void gru_kernel(
    const float* __restrict__ x,        // [B,T,D] f32
    const float* __restrict__ h0,       // [B,H]   f32
    const f16*   __restrict__ Up,
    const f16*   __restrict__ Wp,
    const float* __restrict__ bs,       // [4][H]
    unsigned int* __restrict__ h32,     // [2][64][512] u32 = 2 f16 (double buffer)
    unsigned int* __restrict__ flags,   // [4][64]
    float* __restrict__ out)            // y [B,T,H] then state [B,H]
{
    const int tid = threadIdx.x;
    const int wg  = blockIdx.x;
    const int jb  = wg & 63;     // column-slice 16 j's
    const int bb  = wg >> 6;     // batch-group (16 batches)
    const int w   = tid >> 6;    // wave 0..3 (K-split)
    const int l   = tid & 63;
    const int lrow   = l & 15;   // A row / B col within tile
    const int lchunk = l >> 4;   // k-chunk

    __shared__ float red[4][4][256];   // [wave][tile: z,r,xh,rh][lane*4+i]

    // ---- persistent B fragments in registers ----
    f16x8 uz[8], ur[8], uh[8], wz[2], wr[2], wh[2];
    {
        const f16* ub = Up + (size_t)jb * 3 * 32 * 512;
#pragma unroll
        for (int q = 0; q < 8; ++q) {
            int kt = w * 8 + q;
            uz[q] = *(const f16x8*)(ub + ((size_t)(0 * 32 + kt) * 64 + l) * 8);
            ur[q] = *(const f16x8*)(ub + ((size_t)(1 * 32 + kt) * 64 + l) * 8);
            uh[q] = *(const f16x8*)(ub + ((size_t)(2 * 32 + kt) * 64 + l) * 8);
        }
        const f16* wb = Wp + (size_t)jb * 3 * 8 * 512;
#pragma unroll
        for (int m = 0; m < 2; ++m) {
            int kt = w * 2 + m;
            wz[m] = *(const f16x8*)(wb + ((size_t)(0 * 8 + kt) * 64 + l) * 8);
            wr[m] = *(const f16x8*)(wb + ((size_t)(1 * 8 + kt) * 64 + l) * 8);
            wh[m] = *(const f16x8*)(wb + ((size_t)(2 * 8 + kt) * 64 + l) * 8);
        }
    }

    // ---- gates-phase thread mapping: tid = gb*16 + gj  <->  (batch, j) ----
    const int gb = tid >> 4, gj = tid & 15;
    const int bglob = bb * 16 + gb;
    const int jglob = jb * 16 + gj;
    const float bz  = bs[jglob];
    const float brg = bs[NH + jglob];
    const float bih = bs[2 * NH + jglob];
    const float brh = bs[3 * NH + jglob];
    float hown = h0[(size_t)bglob * NH + jglob];   // f32 master state

    // publish h^0 into buffer 0 (relaxed agent stores -> LLC)
    {
        union { f16 h; unsigned short u; } cv; cv.h = (f16)hown;
        unsigned int hi = (unsigned int)__shfl_down((int)cv.u, 1);
        if ((gj & 1) == 0) {
            unsigned int v = (unsigned int)cv.u | (hi << 16);
            __hip_atomic_store(&h32[(size_t)bglob * 512 + (jglob >> 1)], v,
                               __ATOMIC_RELAXED, __HIP_MEMORY_SCOPE_AGENT);
        }
    }
    asm volatile("s_waitcnt vmcnt(0)" ::: "memory");
    __syncthreads();
    if (tid == 0)
        __hip_atomic_store(&flags[wg], 1u, __ATOMIC_RELAXED, __HIP_MEMORY_SCOPE_AGENT);

    unsigned int* myf = flags + bb * 64;
    const int arow = bb * 16 + lrow;

    for (int t = 0; t < NT; ++t) {
        // ---- x fragments + x-only MFMAs (independent of h^t, before the wait) ----
        f16x8 axm[2];
        const float* xb = x + ((size_t)arow * NT + t) * ND + lchunk * 8;
#pragma unroll
        for (int m = 0; m < 2; ++m) {
            const float* p = xb + (w * 2 + m) * 32;
            f32x4 a0 = *(const f32x4*)p;
            f32x4 a1 = *(const f32x4*)(p + 4);
            f16x8 v;
#pragma unroll
            for (int e = 0; e < 4; ++e) { v[e] = (f16)a0[e]; v[4 + e] = (f16)a1[e]; }
            axm[m] = v;
        }
        f32x4 acc_z = {0,0,0,0}, acc_r = {0,0,0,0}, acc_xh = {0,0,0,0}, acc_rh = {0,0,0,0};
#pragma unroll
        for (int m = 0; m < 2; ++m) {
            acc_z  = __builtin_amdgcn_mfma_f32_16x16x32_f16(axm[m], wz[m], acc_z, 0, 0, 0);
            acc_r  = __builtin_amdgcn_mfma_f32_16x16x32_f16(axm[m], wr[m], acc_r, 0, 0, 0);
            acc_xh = __builtin_amdgcn_mfma_f32_16x16x32_f16(axm[m], wh[m], acc_xh, 0, 0, 0);
        }
        __builtin_amdgcn_sched_barrier(0);

        // ---- wait: all 64 WGs of this batch-group published h^t ----
        // every wave polls independently; no fence (data travels via atomics)
        {
            const unsigned int target = (unsigned int)(t + 1);
            while (!__all((int)(__hip_atomic_load(&myf[l], __ATOMIC_RELAXED,
                                 __HIP_MEMORY_SCOPE_AGENT) >= target))) { }
        }
        asm volatile("" ::: "memory");

        // ---- A fragments: h^t via relaxed agent atomic loads (LLC-direct) ----
        const unsigned int* hb32 = h32 + (size_t)(t & 1) * 32768 + (size_t)arow * 512;
        f16x8 au[8];
#pragma unroll
        for (int q = 0; q < 8; ++q) {
            union { unsigned int u[4]; f16x8 v; } cu;
            const unsigned int* p = hb32 + (w * 8 + q) * 16 + lchunk * 4;
#pragma unroll
            for (int e = 0; e < 4; ++e)
                cu.u[e] = __hip_atomic_load(p + e, __ATOMIC_RELAXED,
                                            __HIP_MEMORY_SCOPE_AGENT);
            au[q] = cu.v;
        }

        // ---- U-part MFMAs ----
#pragma unroll
        for (int q = 0; q < 8; ++q) {
            acc_z  = __builtin_amdgcn_mfma_f32_16x16x32_f16(au[q], uz[q], acc_z, 0, 0, 0);
            acc_r  = __builtin_amdgcn_mfma_f32_16x16x32_f16(au[q], ur[q], acc_r, 0, 0, 0);
            acc_rh = __builtin_amdgcn_mfma_f32_16x16x32_f16(au[q], uh[q], acc_rh, 0, 0, 0);
        }

        // ---- deterministic cross-wave reduction via LDS ----
        *(f32x4*)&red[w][0][l * 4] = acc_z;
        *(f32x4*)&red[w][1][l * 4] = acc_r;
        *(f32x4*)&red[w][2][l * 4] = acc_xh;
        *(f32x4*)&red[w][3][l * 4] = acc_rh;
        __syncthreads();

        const int li = ((((gb >> 2) << 4) | gj) << 2) + (gb & 3);
        float sz = 0.f, sr = 0.f, sxh = 0.f, srh = 0.f;
#pragma unroll
        for (int ww = 0; ww < 4; ++ww) {
            sz  += red[ww][0][li];
            sr  += red[ww][1][li];
            sxh += red[ww][2][li];
            srh += red[ww][3][li];
        }

        // ---- gates ----
        float zg = 1.f / (1.f + __expf(-(sz + bz)));
        float rg = 1.f / (1.f + __expf(-(sr + brg)));
        float ta = sxh + bih + rg * (srh + brh);
        float e2 = __expf(2.f * ta);
        float hh = (e2 - 1.f) / (e2 + 1.f);
        float hn = zg * hown + (1.f - zg) * hh;
        hown = hn;

        // ---- publish h^{t+1} into buffer (t+1)&1, then flag, then out ----
        union { f16 h; unsigned short u; } cv; cv.h = (f16)hn;
        unsigned int hi = (unsigned int)__shfl_down((int)cv.u, 1);
        if ((gj & 1) == 0) {
            unsigned int v = (unsigned int)cv.u | (hi << 16);
            __hip_atomic_store(&h32[(size_t)((t + 1) & 1) * 32768 +
                                    (size_t)bglob * 512 + (jglob >> 1)], v,
                               __ATOMIC_RELAXED, __HIP_MEMORY_SCOPE_AGENT);
        }
        asm volatile("s_waitcnt vmcnt(0)" ::: "memory");  // h stores at LLC
        __syncthreads();                                   // all waves done
        if (tid == 0)
            __hip_atomic_store(&flags[wg], (unsigned int)(t + 2),
                               __ATOMIC_RELAXED, __HIP_MEMORY_SCOPE_AGENT);
        // out store off the critical chain
        out[((size_t)bglob * NT + t) * NH + jglob] = hn;
    }

    // final state
    out[(size_t)NB * NT * NH + (size_t)bglob * NH + jglob] = hown;
}

extern "C" void kernel_launch(void* const* d_in, const int* in_sizes, int n_in,
                              void* d_out, int out_size, void* d_ws, size_t ws_size,
                              hipStream_t stream) {
    const float* x  = (const float*)d_in[0];
    const float* h0 = (const float*)d_in[1];
    const float* W  = (const float*)d_in[2];
    const float* U  = (const float*)d_in[3];
    const float* bi = (const float*)d_in[4];
    const float* br = (const float*)d_in[5];
    float* out = (float*)d_out;

    char* ws = (char*)d_ws;
    f16* Up             = (f16*)ws;                                   // 6,291,456 B
    f16* Wp             = (f16*)(ws + 6291456);                       // 1,572,864 B
    float* bs           = (float*)(ws + 6291456 + 1572864);           // 16 KB
    unsigned int* h32   = (unsigned int*)(ws + 6291456 + 1572864 + 16384);          // 256 KB
    unsigned int* flags = (unsigned int*)(ws + 6291456 + 1572864 + 16384 + 262144); // 1 KB

    hipMemsetAsync(flags, 0, 256 * sizeof(unsigned int), stream);
    pack_u_kernel<<<1536, 256, 0, stream>>>(U, Up);
    pack_w_kernel<<<384, 256, 0, stream>>>(W, Wp);
    bias_kernel<<<1, 1024, 0, stream>>>(bi, br, bs);

    void* args[] = { (void*)&x, (void*)&h0, (void*)&Up, (void*)&Wp, (void*)&bs,
                     (void*)&h32, (void*)&flags, (void*)&out };
    hipLaunchCooperativeKernel((const void*)gru_kernel, dim3(256), dim3(256),
                               args, 0, stream);
}

// Round 3
// 1947.305 us; speedup vs baseline: 2.3308x; 1.9254x over previous
//
#include <hip/hip_runtime.h>
#include <hip/hip_fp16.h>

// GRU (Keras reset_after=True), B=64 T=512 D=256 H=1024.
// Persistent cooperative kernel: 256 WGs (1/CU), weights register-resident.
// Cross-WG step protocol: h via sc0sc1 (coherence-point) vector load/store,
// flags via relaxed agent atomics; ordering via explicit s_waitcnt vmcnt(0).
// out buffered 8 steps in registers, burst nt stores off the critical chain.

#define NB 64
#define NT 512
#define ND 256
#define NH 1024
#define NG 3072  // 3H

typedef _Float16 f16;
typedef __attribute__((ext_vector_type(8))) _Float16 f16x8;
typedef __attribute__((ext_vector_type(4))) float f32x4;

// ---- prep: pack U [H,3H] f32 -> fragment-layout f16 ----
// Up index: (((jb*3 + g)*32 + kt)*64 + l)*8 + e
// value  : U[k][col], k = kt*32 + (l>>4)*8 + e, col = g*NH + jb*16 + (l&15)
__global__ void pack_u_kernel(const float* __restrict__ U, f16* __restrict__ Up) {
    int idx = blockIdx.x * 256 + threadIdx.x;      // 64*3*32*64 = 393216
    int l  = idx & 63;
    int kt = (idx >> 6) & 31;
    int r  = idx >> 11;                            // jb*3 + g
    int g  = r % 3, jb = r / 3;
    int col = g * NH + jb * 16 + (l & 15);
    int k0  = kt * 32 + (l >> 4) * 8;
    f16x8 v;
#pragma unroll
    for (int e = 0; e < 8; ++e) v[e] = (f16)U[(size_t)(k0 + e) * NG + col];
    *(f16x8*)(Up + (size_t)idx * 8) = v;
}

// Wp index: (((jb*3 + g)*8 + kt)*64 + l)*8 + e  (K=256 -> 8 ktiles)
__global__ void pack_w_kernel(const float* __restrict__ W, f16* __restrict__ Wp) {
    int idx = blockIdx.x * 256 + threadIdx.x;      // 64*3*8*64 = 98304
    int l  = idx & 63;
    int kt = (idx >> 6) & 7;
    int r  = idx >> 9;
    int g  = r % 3, jb = r / 3;
    int col = g * NH + jb * 16 + (l & 15);
    int k0  = kt * 32 + (l >> 4) * 8;
    f16x8 v;
#pragma unroll
    for (int e = 0; e < 8; ++e) v[e] = (f16)W[(size_t)(k0 + e) * NG + col];
    *(f16x8*)(Wp + (size_t)idx * 8) = v;
}

// bs[0..H): bi_z+br_z ; bs[H..2H): bi_r+br_r ; bs[2H..3H): bi_h ; bs[3H..4H): br_h
__global__ void bias_kernel(const float* __restrict__ bi, const float* __restrict__ br,
                            float* __restrict__ bs) {
    int j = threadIdx.x;  // 1024
    bs[j]          = bi[j] + br[j];
    bs[NH + j]     = bi[NH + j] + br[NH + j];
    bs[2 * NH + j] = bi[2 * NH + j];
    bs[3 * NH + j] = br[2 * NH + j];
}

// coherence-point (LLC) 16B load / 4B store: bypass L1+L2 so cross-XCD
// producer/consumer works without acquire/release cache maintenance.
__device__ __forceinline__ f16x8 llc_load16(const void* p) {
    f16x8 r;
    asm volatile("global_load_dwordx4 %0, %1, off sc0 sc1"
                 : "=v"(r) : "v"(p));
    return r;
}
__device__ __forceinline__ void llc_store4(void* p, unsigned int v) {
    asm volatile("global_store_dword %0, %1, off sc0 sc1"
                 :: "v"(p), "v"(v));
}

__global__ __launch_bounds__(256, 1) void gru_kernel(
    const float* __restrict__ x,        // [B,T,D] f32
    const float* __restrict__ h0,       // [B,H]   f32
    const f16*   __restrict__ Up,
    const f16*   __restrict__ Wp,
    const float* __restrict__ bs,       // [4][H]
    unsigned int* __restrict__ h32,     // [2][64][512] u32 = 2 f16 (double buffer)
    unsigned int* __restrict__ flags,   // [4][64]
    float* __restrict__ out)            // y [B,T,H] then state [B,H]
{
    const int tid = threadIdx.x;
    const int wg  = blockIdx.x;
    const int jb  = wg & 63;     // column-slice 16 j's
    const int bb  = wg >> 6;     // batch-group (16 batches)
    const int w   = tid >> 6;    // wave 0..3 (K-split)
    const int l   = tid & 63;
    const int lrow   = l & 15;   // A row / B col within tile
    const int lchunk = l >> 4;   // k-chunk

    __shared__ float red[4][4][256];   // [wave][tile: z,r,xh,rh][lane*4+i]

    // ---- persistent B fragments in registers ----
    f16x8 uz[8], ur[8], uh[8], wz[2], wr[2], wh[2];
    {
        const f16* ub = Up + (size_t)jb * 3 * 32 * 512;
#pragma unroll
        for (int q = 0; q < 8; ++q) {
            int kt = w * 8 + q;
            uz[q] = *(const f16x8*)(ub + ((size_t)(0 * 32 + kt) * 64 + l) * 8);
            ur[q] = *(const f16x8*)(ub + ((size_t)(1 * 32 + kt) * 64 + l) * 8);
            uh[q] = *(const f16x8*)(ub + ((size_t)(2 * 32 + kt) * 64 + l) * 8);
        }
        const f16* wb = Wp + (size_t)jb * 3 * 8 * 512;
#pragma unroll
        for (int m = 0; m < 2; ++m) {
            int kt = w * 2 + m;
            wz[m] = *(const f16x8*)(wb + ((size_t)(0 * 8 + kt) * 64 + l) * 8);
            wr[m] = *(const f16x8*)(wb + ((size_t)(1 * 8 + kt) * 64 + l) * 8);
            wh[m] = *(const f16x8*)(wb + ((size_t)(2 * 8 + kt) * 64 + l) * 8);
        }
    }

    // ---- gates-phase thread mapping: tid = gb*16 + gj  <->  (batch, j) ----
    const int gb = tid >> 4, gj = tid & 15;
    const int bglob = bb * 16 + gb;
    const int jglob = jb * 16 + gj;
    const float bz  = bs[jglob];
    const float brg = bs[NH + jglob];
    const float bih = bs[2 * NH + jglob];
    const float brh = bs[3 * NH + jglob];
    float hown = h0[(size_t)bglob * NH + jglob];   // f32 master state

    // publish h^0 into buffer 0
    {
        union { f16 h; unsigned short u; } cv; cv.h = (f16)hown;
        unsigned int hi = (unsigned int)__shfl_down((int)cv.u, 1);
        if ((gj & 1) == 0)
            llc_store4(&h32[(size_t)bglob * 512 + (jglob >> 1)],
                       (unsigned int)cv.u | (hi << 16));
    }
    asm volatile("s_waitcnt vmcnt(0)" ::: "memory");
    __syncthreads();
    if (tid == 0)
        __hip_atomic_store(&flags[wg], 1u, __ATOMIC_RELAXED, __HIP_MEMORY_SCOPE_AGENT);

    unsigned int* myf = flags + bb * 64;
    const int arow = bb * 16 + lrow;

    float ybuf[8];

    for (int tb = 0; tb < NT / 8; ++tb) {
#pragma unroll
        for (int tt = 0; tt < 8; ++tt) {
            const int t = tb * 8 + tt;

            // ---- x fragments + x-only MFMAs (independent of h^t) ----
            f16x8 axm[2];
            const float* xb = x + ((size_t)arow * NT + t) * ND + lchunk * 8;
#pragma unroll
            for (int m = 0; m < 2; ++m) {
                const float* p = xb + (w * 2 + m) * 32;
                f32x4 a0 = *(const f32x4*)p;
                f32x4 a1 = *(const f32x4*)(p + 4);
                f16x8 v;
#pragma unroll
                for (int e = 0; e < 4; ++e) { v[e] = (f16)a0[e]; v[4 + e] = (f16)a1[e]; }
                axm[m] = v;
            }
            f32x4 acc_z = {0,0,0,0}, acc_r = {0,0,0,0};
            f32x4 acc_xh = {0,0,0,0}, acc_rh = {0,0,0,0};
#pragma unroll
            for (int m = 0; m < 2; ++m) {
                acc_z  = __builtin_amdgcn_mfma_f32_16x16x32_f16(axm[m], wz[m], acc_z, 0, 0, 0);
                acc_r  = __builtin_amdgcn_mfma_f32_16x16x32_f16(axm[m], wr[m], acc_r, 0, 0, 0);
                acc_xh = __builtin_amdgcn_mfma_f32_16x16x32_f16(axm[m], wh[m], acc_xh, 0, 0, 0);
            }
            __builtin_amdgcn_sched_barrier(0);

            // ---- wait: all 64 WGs of this batch-group published h^t ----
            {
                const unsigned int target = (unsigned int)(t + 1);
                while (!__all((int)(__hip_atomic_load(&myf[l], __ATOMIC_RELAXED,
                                     __HIP_MEMORY_SCOPE_AGENT) >= target))) { }
            }
            asm volatile("" ::: "memory");

            // ---- A fragments: h^t via coalesced LLC vector loads ----
            const unsigned int* hb32 =
                h32 + (size_t)(t & 1) * 32768 + (size_t)arow * 512;
            f16x8 au[8];
#pragma unroll
            for (int q = 0; q < 8; ++q)
                au[q] = llc_load16(hb32 + (w * 8 + q) * 16 + lchunk * 4);
            asm volatile("s_waitcnt vmcnt(0)" ::: "memory");
            __builtin_amdgcn_sched_barrier(0);

            // ---- U-part MFMAs ----
#pragma unroll
            for (int q = 0; q < 8; ++q) {
                acc_z  = __builtin_amdgcn_mfma_f32_16x16x32_f16(au[q], uz[q], acc_z, 0, 0, 0);
                acc_r  = __builtin_amdgcn_mfma_f32_16x16x32_f16(au[q], ur[q], acc_r, 0, 0, 0);
                acc_rh = __builtin_amdgcn_mfma_f32_16x16x32_f16(au[q], uh[q], acc_rh, 0, 0, 0);
            }

            // ---- deterministic cross-wave reduction via LDS ----
            *(f32x4*)&red[w][0][l * 4] = acc_z;
            *(f32x4*)&red[w][1][l * 4] = acc_r;
            *(f32x4*)&red[w][2][l * 4] = acc_xh;
            *(f32x4*)&red[w][3][l * 4] = acc_rh;
            __syncthreads();

            const int li = ((((gb >> 2) << 4) | gj) << 2) + (gb & 3);
            float sz = 0.f, sr = 0.f, sxh = 0.f, srh = 0.f;
#pragma unroll
            for (int ww = 0; ww < 4; ++ww) {
                sz  += red[ww][0][li];
                sr  += red[ww][1][li];
                sxh += red[ww][2][li];
                srh += red[ww][3][li];
            }

            // ---- gates ----
            float zg = 1.f / (1.f + __expf(-(sz + bz)));
            float rg = 1.f / (1.f + __expf(-(sr + brg)));
            float ta = sxh + bih + rg * (srh + brh);
            float e2 = __expf(2.f * ta);
            float hh = (e2 - 1.f) / (e2 + 1.f);
            float hn = zg * hown + (1.f - zg) * hh;
            hown = hn;
            ybuf[tt] = hn;

            // ---- publish h^{t+1}, drain, flag ----
            union { f16 h; unsigned short u; } cv; cv.h = (f16)hn;
            unsigned int hi = (unsigned int)__shfl_down((int)cv.u, 1);
            if ((gj & 1) == 0)
                llc_store4(&h32[(size_t)((t + 1) & 1) * 32768 +
                                (size_t)bglob * 512 + (jglob >> 1)],
                           (unsigned int)cv.u | (hi << 16));
            asm volatile("s_waitcnt vmcnt(0)" ::: "memory");  // h stores at LLC
            __syncthreads();                                   // all waves done
            if (tid == 0)
                __hip_atomic_store(&flags[wg], (unsigned int)(t + 2),
                                   __ATOMIC_RELAXED, __HIP_MEMORY_SCOPE_AGENT);
        }

        // ---- burst 8 steps of y with non-temporal stores (off critical chain) ----
        float* yb = out + ((size_t)bglob * NT + tb * 8) * NH + jglob;
#pragma unroll
        for (int tt = 0; tt < 8; ++tt)
            __builtin_nontemporal_store(ybuf[tt], yb + (size_t)tt * NH);
    }

    // final state
    out[(size_t)NB * NT * NH + (size_t)bglob * NH + jglob] = hown;
}

extern "C" void kernel_launch(void* const* d_in, const int* in_sizes, int n_in,
                              void* d_out, int out_size, void* d_ws, size_t ws_size,
                              hipStream_t stream) {
    const float* x  = (const float*)d_in[0];
    const float* h0 = (const float*)d_in[1];
    const float* W  = (const float*)d_in[2];
    const float* U  = (const float*)d_in[3];
    const float* bi = (const float*)d_in[4];
    const float* br = (const float*)d_in[5];
    float* out = (float*)d_out;

    char* ws = (char*)d_ws;
    f16* Up             = (f16*)ws;                                   // 6,291,456 B
    f16* Wp             = (f16*)(ws + 6291456);                       // 1,572,864 B
    float* bs           = (float*)(ws + 6291456 + 1572864);           // 16 KB
    unsigned int* h32   = (unsigned int*)(ws + 6291456 + 1572864 + 16384);          // 256 KB
    unsigned int* flags = (unsigned int*)(ws + 6291456 + 1572864 + 16384 + 262144); // 1 KB

    hipMemsetAsync(flags, 0, 256 * sizeof(unsigned int), stream);
    pack_u_kernel<<<1536, 256, 0, stream>>>(U, Up);
    pack_w_kernel<<<384, 256, 0, stream>>>(W, Wp);
    bias_kernel<<<1, 1024, 0, stream>>>(bi, br, bs);

    void* args[] = { (void*)&x, (void*)&h0, (void*)&Up, (void*)&Wp, (void*)&bs,
                     (void*)&h32, (void*)&flags, (void*)&out };
    hipLaunchCooperativeKernel((const void*)gru_kernel, dim3(256), dim3(256),
                               args, 0, stream);
}